// Round 6
// baseline (429.580 us; speedup 1.0000x reference)
//
#include <hip/hip_runtime.h>
#include <hip/hip_bf16.h>
#include <cmath>
#include <complex>

#define NT 512

typedef __bf16 bf16x8 __attribute__((ext_vector_type(8)));
typedef float  f32x4  __attribute__((ext_vector_type(4)));

struct CgPack { float v[363]; };

// ======================= host-side Wigner 3j (e3nn convention) =======================
static double factd(int n) { double r = 1.0; for (int i = 2; i <= n; ++i) r *= i; return r; }

static void su2_cg(int j1, int j2, int j3, double C[5][5][5]) {
  for (int a = 0; a < 5; ++a) for (int b = 0; b < 5; ++b) for (int c = 0; c < 5; ++c) C[a][b][c] = 0.0;
  for (int m1 = -j1; m1 <= j1; ++m1)
    for (int m2 = -j2; m2 <= j2; ++m2) {
      int m3 = m1 + m2;
      if (m3 < -j3 || m3 > j3) continue;
      int vmin = -j1 + j2 + m3; if (-j1 + m1 > vmin) vmin = -j1 + m1; if (vmin < 0) vmin = 0;
      int vmax = j2 + j3 + m1; if (j3 - j1 + j2 < vmax) vmax = j3 - j1 + j2; if (j3 + m3 < vmax) vmax = j3 + m3;
      double c = std::sqrt((2.0 * j3 + 1.0) *
            factd(j3 + j1 - j2) * factd(j3 - j1 + j2) * factd(j1 + j2 - j3) * factd(j3 + m3) * factd(j3 - m3) /
            (factd(j1 + j2 + j3 + 1) * factd(j1 - m1) * factd(j1 + m1) * factd(j2 - m2) * factd(j2 + m2)));
      double S = 0.0;
      for (int v = vmin; v <= vmax; ++v) {
        double t = factd(j2 + j3 + m1 - v) * factd(j1 - m1 + v) /
                   (factd(v) * factd(j3 - j1 + j2 - v) * factd(j3 + m3 - v) * factd(v + j1 - j2 - m3));
        S += (((v + j2 + m2) & 1) ? -t : t);
      }
      C[j1 + m1][j2 + m2][j3 + m3] = c * S;
    }
}

typedef std::complex<double> cd;
static void qmat(int l, cd q[5][5]) {
  for (int a = 0; a < 5; ++a) for (int b = 0; b < 5; ++b) q[a][b] = cd(0.0, 0.0);
  const double is2 = 1.0 / std::sqrt(2.0);
  for (int m = -l; m < 0; ++m) { q[l + m][l - m] = cd(is2, 0.0); q[l + m][l + m] = cd(0.0, -is2); }
  q[l][l] = cd(1.0, 0.0);
  for (int m = 1; m <= l; ++m) {
    double sg = (m & 1) ? -1.0 : 1.0;
    q[l + m][l + m] = cd(sg * is2, 0.0);
    q[l + m][l - m] = cd(0.0, sg * is2);
  }
  cd ph(1.0, 0.0); const cd mi(0.0, -1.0);
  for (int t = 0; t < l; ++t) ph *= mi;   // (-i)^l
  for (int a = 0; a <= 2 * l; ++a) for (int b = 0; b <= 2 * l; ++b) q[a][b] *= ph;
}

static void w3j_fill(int l1, int l2, int l3, float* outp) {
  double C[5][5][5]; su2_cg(l1, l2, l3, C);
  cd q1[5][5], q2[5][5], q3[5][5];
  qmat(l1, q1); qmat(l2, q2); qmat(l3, q3);
  const int d1 = 2 * l1 + 1, d2 = 2 * l2 + 1, d3 = 2 * l3 + 1;
  double R[5][5][5]; double nrm = 0.0;
  for (int j = 0; j < d1; ++j)
    for (int L = 0; L < d2; ++L)
      for (int m = 0; m < d3; ++m) {
        cd s(0.0, 0.0);
        for (int i = 0; i < d1; ++i)
          for (int k = 0; k < d2; ++k)
            for (int n = 0; n < d3; ++n)
              s += q1[i][j] * q2[k][L] * std::conj(q3[n][m]) * C[i][k][n];
        R[j][L][m] = s.real();
        nrm += s.real() * s.real();
      }
  const double inv = 1.0 / std::sqrt(nrm);
  for (int j = 0; j < d1; ++j)
    for (int L = 0; L < d2; ++L)
      for (int m = 0; m < d3; ++m)
        outp[(j * d2 + L) * d3 + m] = (float)(R[j][L][m] * inv);
}

static void build_cg(CgPack* cg) {
  const int L1[11] = {0,0,0,1,1,1,1,2,2,2,2};
  const int L2[11] = {0,1,2,0,1,1,2,0,1,2,2};
  const int L3[11] = {0,1,2,1,0,2,1,2,1,0,2};
  const int CGO[11]= {0,1,10,35,44,53,98,143,168,213,238};
  for (int p = 0; p < 11; ++p) w3j_fill(L1[p], L2[p], L3[p], &cg->v[CGO[p]]);
}

// ======================= device-side path constants =======================
constexpr int cP_l1[11] = {0,0,0,1,1,1,1,2,2,2,2};
constexpr int cP_l2[11] = {0,1,2,0,1,1,2,0,1,2,2};
constexpr int cP_l3[11] = {0,1,2,1,0,2,1,2,1,0,2};
constexpr int cP_wo[11] = {0,1024,1536,1792,2048,2560,2688,2944,3008,3136,3392};
constexpr int cP_cgo[11]= {0,1,10,35,44,53,98,143,168,213,238};
constexpr int mul_of_l(int l)    { return l == 0 ? 32 : (l == 1 ? 16 : 8); }
constexpr int off_in_of_l(int l) { return l == 0 ? 0  : (l == 1 ? 32 : 80); }
constexpr int off_sh_of_l(int l) { return l == 0 ? 0  : (l == 1 ? 1  : 4); }

__device__ __forceinline__ float silu_f(float x) { return x / (1.0f + __expf(-x)); }

// one 16-col x 16-edge MFMA tile + immediate register contract.
// bias b3 is folded into the accumulator init (dd = b3), shortening the dep chain.
template<int wo, int m3, int d3>
__device__ __forceinline__ void tile_mm(
    const __bf16* __restrict__ w3b, const float* __restrict__ b3,
    const float* tmpw, const bf16x8 hB0, const bf16x8 hB1,
    const int u0, const int tt, const int uu, const int lr, const int lc,
    float (&acc)[4*d3])
{
  const int cb = wo + u0*m3 + tt*16;                    // global col base of tile
  const float4 b4 = *(const float4*)(b3 + cb + lr*4);   // bias for this lane's 4 cols
  const __bf16* ap = w3b + (size_t)(cb + lc)*64 + lr*8; // A = w3 tile
  const bf16x8 a0 = *(const bf16x8*)ap;                 // k = lr*8..+8
  const bf16x8 a1 = *(const bf16x8*)(ap + 32);          // k = 32+lr*8..+8
  f32x4 dd = {b4.x, b4.y, b4.z, b4.w};
  dd = __builtin_amdgcn_mfma_f32_16x16x32_bf16(a0, hB0, dd, 0, 0, 0);
  dd = __builtin_amdgcn_mfma_f32_16x16x32_bf16(a1, hB1, dd, 0, 0, 0);
  // D[w3col = lr*4+r][edge = lc]; dd already includes b3
  float tv[d3];
  #pragma unroll
  for (int k = 0; k < d3; ++k) tv[k] = tmpw[(uu*d3 + k)*16 + lc];
  #pragma unroll
  for (int r = 0; r < 4; ++r) {
    #pragma unroll
    for (int k = 0; k < d3; ++k) acc[r*d3 + k] += dd[r] * tv[k];
  }
}

// one tensor-product path, fully wave-local; wave handles u-blocks ub0, ub0+ubstep, ...
template<int P>
__device__ __forceinline__ void wave_path(
    const CgPack& cg, const __bf16* __restrict__ w3b, const float* __restrict__ b3,
    const float* __restrict__ nf, const int* esrc, float (&x2s)[32][13],
    float* tmpw, float (&msg)[32][121],
    const bf16x8 hB0, const bf16x8 hB1, const int g, const int lane,
    const int ub0, const int ubstep)
{
  constexpr int l1 = cP_l1[P], l2 = cP_l2[P], l3 = cP_l3[P];
  constexpr int m1 = mul_of_l(l1), m3 = mul_of_l(l3);
  constexpr int d1 = 2*l1+1, d2 = 2*l2+1, d3 = 2*l3+1;
  constexpr int off1 = off_in_of_l(l1);
  constexpr int off2 = off_sh_of_l(l2);
  constexpr int off3 = off_in_of_l(l3);
  constexpr int wo = cP_wo[P], cgo = cP_cgo[P];
  constexpr float coeff = (l3==0) ? 0.13363062095621219f
                         : (l3==1) ? 0.20412414523193154f
                                   : 0.27950849718747373f;
  constexpr int UBLK = 4;                      // u's per tmp block (tmp rows = 4*d3 <= 20)
  constexpr int NUB  = m1 / UBLK;
  constexpr int NTIL = UBLK * m3 / 16;         // 16-col tiles per u-block: 8/4/2

  const int lr = lane >> 4, lc = lane & 15;
  const int e  = g*16 + lc;                    // this lane's edge (block-local)

  float accA[4*d3];
  float accB[(m3==32) ? 4 : 1];
  #pragma unroll
  for (int i = 0; i < 4*d3; ++i) accA[i] = 0.0f;
  #pragma unroll
  for (int i = 0; i < ((m3==32) ? 4 : 1); ++i) accB[i] = 0.0f;

  for (int ub = ub0; ub < NUB; ub += ubstep) {
    const int u0 = ub * UBLK;
    // ---- tmp build (wave-local LDS): 64 lanes = 16 edges x 4 u's, one pass
    {
      const int te = lane & 15, uu = lane >> 4;
      const float* xr = nf + (size_t)esrc[g*16 + te] * 120 + (off1 + (u0 + uu)*d1);
      float t[d3];
      #pragma unroll
      for (int k = 0; k < d3; ++k) t[k] = 0.0f;
      #pragma unroll
      for (int i = 0; i < d1; ++i) {
        const float a = xr[i];
        #pragma unroll
        for (int j = 0; j < d2; ++j) {
          const float ab = a * x2s[g*16 + te][off2 + j];
          #pragma unroll
          for (int k = 0; k < d3; ++k) t[k] += ab * cg.v[cgo + (i*d2 + j)*d3 + k];
        }
      }
      #pragma unroll
      for (int k = 0; k < d3; ++k) tmpw[(uu*d3 + k)*16 + te] = t[k];
    }
    // (same-wave LDS producer/consumer: hardware processes DS ops in order; lgkmcnt waits inserted)

    // ---- tile loop: MFMA + immediate contract
    if constexpr (m3 == 32) {
      #pragma unroll
      for (int tt = 0; tt < NTIL; tt += 2) {
        tile_mm<wo, m3, d3>(w3b, b3, tmpw, hB0, hB1, u0, tt,   tt>>1, lr, lc, accA);
        tile_mm<wo, m3, d3>(w3b, b3, tmpw, hB0, hB1, u0, tt+1, tt>>1, lr, lc, accB);
      }
    } else {
      #pragma unroll
      for (int tt = 0; tt < NTIL; ++tt) {
        const int uu = (m3 == 16) ? tt : (2*tt + (lr >> 1));
        tile_mm<wo, m3, d3>(w3b, b3, tmpw, hB0, hB1, u0, tt, uu, lr, lc, accA);
      }
    }
  }

  // ---- flush into msg (LDS atomics)
  if constexpr (m3 == 16) {
    #pragma unroll
    for (int r = 0; r < 4; ++r)
      #pragma unroll
      for (int k = 0; k < d3; ++k)
        atomicAdd(&msg[e][off3 + (lr*4 + r)*d3 + k], coeff * accA[r*d3 + k]);
  } else if constexpr (m3 == 8) {
    #pragma unroll
    for (int i = 0; i < 4*d3; ++i) accA[i] += __shfl_xor(accA[i], 32, 64);
    if (lane < 32) {   // lr in {0,1}: v = lr*4+r covers 0..7
      #pragma unroll
      for (int r = 0; r < 4; ++r)
        #pragma unroll
        for (int k = 0; k < d3; ++k)
          atomicAdd(&msg[e][off3 + (lr*4 + r)*d3 + k], coeff * accA[r*d3 + k]);
    }
  } else {  // m3 == 32, d3 == 1
    #pragma unroll
    for (int r = 0; r < 4; ++r) {
      atomicAdd(&msg[e][off3 +      lr*4 + r], coeff * accA[r]);
      atomicAdd(&msg[e][off3 + 16 + lr*4 + r], coeff * accB[r]);
    }
  }
}

// ======================= w3 -> bf16 (col-major, K-contiguous) =======================
__global__ __launch_bounds__(256)
void conv_w3(const float* __restrict__ w3, __bf16* __restrict__ w3b, const int n) {
  const int idx = blockIdx.x * 256 + threadIdx.x;
  if (idx >= n) return;
  const int k = idx / 3456, col = idx - k * 3456;
  w3b[(size_t)col * 64 + k] = (__bf16)w3[idx];
}

// ======================= fused MLP + TP + scatter kernel =======================
// 32 edges/block, 8 waves: wave = (edge-group g in {0,1}) x (col-quarter q in {0..3})
__global__ __launch_bounds__(NT, 8)
void tp_fused(const float* __restrict__ nf, const int* __restrict__ eidx,
              const float* __restrict__ sh, const float* __restrict__ rad,
              const float* __restrict__ w1, const float* __restrict__ b1,
              const float* __restrict__ w2, const float* __restrict__ b2,
              const __bf16* __restrict__ w3b, const float* __restrict__ b3,
              float* __restrict__ agg, const int E, const CgPack cg)
{
  __shared__ float msg[32][121];      // per-edge message accumulator (15.5 KB); prologue: h1T
  __shared__ float x2s[32][13];       // edge SH (1.7 KB)
  __shared__ float tmparea[8][320];   // per-wave tmp regions (10.24 KB); prologue: h2b
  __shared__ int   esrc[32], edst[32];

  const int tid  = threadIdx.x;
  const int lane = tid & 63, w = tid >> 6;
  const int g = w & 1, q = w >> 1;
  const int lr = lane >> 4, lc = lane & 15;
  const int e0 = blockIdx.x * 32;

  float*  h1T = &msg[0][0];                    // 64x32 f32 (8 KB), h1T[c*32+e]
  __bf16* h2b = (__bf16*)&tmparea[0][0];       // 32x64 bf16 (4 KB), h2b[e*64+k]

  // ---- phase A: indices, h1 = silu(rad@w1+b1) -> h1T, x2 stage
  if (tid < 32)      esrc[tid]      = eidx[e0 + tid];
  else if (tid < 64) edst[tid - 32] = eidx[E + e0 + tid - 32];
  for (int idx = tid; idx < 64 * 32; idx += NT) {
    const int c = idx >> 5, e = idx & 31;
    const float4* r4 = (const float4*)(rad + (size_t)(e0 + e) * 8);
    const float4 ra = r4[0], rb = r4[1];
    float a = b1[c];
    a += ra.x * w1[0*64+c] + ra.y * w1[1*64+c] + ra.z * w1[2*64+c] + ra.w * w1[3*64+c];
    a += rb.x * w1[4*64+c] + rb.y * w1[5*64+c] + rb.z * w1[6*64+c] + rb.w * w1[7*64+c];
    h1T[c * 32 + e] = silu_f(a);
  }
  for (int idx = tid; idx < 32 * 9; idx += NT) {
    const int e = idx / 9, j = idx - e * 9;
    x2s[e][j] = sh[(size_t)(e0 + e) * 9 + j];
  }
  __syncthreads();

  // ---- phase B: h2 = silu(h1@w2+b2) -> h2b[e][k] (bf16, k-contiguous); 512 tasks = 1 pass
  {
    const int c = tid >> 3, eq = (tid & 7) * 4;
    float a0 = b2[c], a1 = b2[c], a2 = b2[c], a3 = b2[c];
    #pragma unroll 8
    for (int i = 0; i < 64; ++i) {
      const float wv = w2[i * 64 + c];
      const float4 h4 = *(const float4*)(&h1T[i * 32 + eq]);
      a0 += h4.x * wv; a1 += h4.y * wv; a2 += h4.z * wv; a3 += h4.w * wv;
    }
    h2b[(eq+0)*64 + c] = (__bf16)silu_f(a0);
    h2b[(eq+1)*64 + c] = (__bf16)silu_f(a1);
    h2b[(eq+2)*64 + c] = (__bf16)silu_f(a2);
    h2b[(eq+3)*64 + c] = (__bf16)silu_f(a3);
  }
  __syncthreads();

  // ---- per-wave B-fragments: lane holds h2[e = g*16+lc][k = kb*32 + lr*8 + j]
  const bf16x8 hB0 = *(const bf16x8*)(h2b + (g*16 + lc)*64 +      lr*8);
  const bf16x8 hB1 = *(const bf16x8*)(h2b + (g*16 + lc)*64 + 32 + lr*8);
  // zero msg (h1T dead now)
  for (int idx = tid; idx < 32 * 121; idx += NT) (&msg[0][0])[idx] = 0.0f;
  __syncthreads();   // h2b consumed + msg zeroed; tmparea free

  float* tmpw = tmparea[w];

  // ---- paths: u-blocks round-robin across the 4 quarters (zero duplication)
  // NUB=8 paths (p0,p1,p2): 2 u-blocks each; NUB=4 (p3..p6): 1 each; NUB=2 (p7..p10): paired.
  wave_path<0>(cg, w3b, b3, nf, esrc, x2s, tmpw, msg, hB0, hB1, g, lane, q, 4);
  wave_path<1>(cg, w3b, b3, nf, esrc, x2s, tmpw, msg, hB0, hB1, g, lane, q, 4);
  wave_path<2>(cg, w3b, b3, nf, esrc, x2s, tmpw, msg, hB0, hB1, g, lane, q, 4);
  wave_path<3>(cg, w3b, b3, nf, esrc, x2s, tmpw, msg, hB0, hB1, g, lane, q, 4);
  wave_path<4>(cg, w3b, b3, nf, esrc, x2s, tmpw, msg, hB0, hB1, g, lane, q, 4);
  wave_path<5>(cg, w3b, b3, nf, esrc, x2s, tmpw, msg, hB0, hB1, g, lane, q, 4);
  wave_path<6>(cg, w3b, b3, nf, esrc, x2s, tmpw, msg, hB0, hB1, g, lane, q, 4);
  if (q < 2) {
    wave_path<7>(cg, w3b, b3, nf, esrc, x2s, tmpw, msg, hB0, hB1, g, lane, q, 2);
    wave_path<9>(cg, w3b, b3, nf, esrc, x2s, tmpw, msg, hB0, hB1, g, lane, q, 2);
  } else {
    wave_path<8>(cg, w3b, b3, nf, esrc, x2s, tmpw, msg, hB0, hB1, g, lane, q-2, 2);
    wave_path<10>(cg, w3b, b3, nf, esrc, x2s, tmpw, msg, hB0, hB1, g, lane, q-2, 2);
  }
  __syncthreads();   // all msg flushes complete

  // ---- scatter: agg[dst] += msg
  for (int idx = tid; idx < 32 * 120; idx += NT) {
    const int e = idx / 120, d = idx - e * 120;
    atomicAdd(&agg[(size_t)edst[e] * 120 + d], msg[e][d]);
  }
}

// ======================= self-interaction + residual =======================
__global__ __launch_bounds__(128)
void si_kernel(const float* __restrict__ agg, const float* __restrict__ nf,
               const float* __restrict__ w0, const float* __restrict__ wl1,
               const float* __restrict__ wl2, float* __restrict__ out)
{
  __shared__ float a[120];
  const int n = blockIdx.x, tid = threadIdx.x;
  if (tid < 120) a[tid] = agg[(size_t)n * 120 + tid];
  __syncthreads();
  if (tid >= 120) return;
  float s = 0.0f;
  if (tid < 32) {
    const int v = tid;
    #pragma unroll
    for (int u = 0; u < 32; ++u) s += a[u] * w0[u * 32 + v];
    s *= 0.17677669529663687f;    // 1/sqrt(32)
  } else if (tid < 80) {
    const int r = tid - 32, v = r / 3, k = r - 3 * v;
    #pragma unroll
    for (int u = 0; u < 16; ++u) s += a[32 + u * 3 + k] * wl1[u * 16 + v];
    s *= 0.25f;                   // 1/sqrt(16)
  } else {
    const int r = tid - 80, v = r / 5, k = r - 5 * v;
    #pragma unroll
    for (int u = 0; u < 8; ++u) s += a[80 + u * 5 + k] * wl2[u * 8 + v];
    s *= 0.35355339059327373f;    // 1/sqrt(8)
  }
  out[(size_t)n * 120 + tid] = s + nf[(size_t)n * 120 + tid];
}

// ======================= launch =======================
extern "C" void kernel_launch(void* const* d_in, const int* in_sizes, int n_in,
                              void* d_out, int out_size, void* d_ws, size_t ws_size,
                              hipStream_t stream) {
  const float* nf  = (const float*)d_in[0];
  const int*   ei  = (const int*)  d_in[1];
  const float* sh  = (const float*)d_in[2];
  const float* rad = (const float*)d_in[3];
  const float* w1  = (const float*)d_in[4];
  const float* b1  = (const float*)d_in[5];
  const float* w2  = (const float*)d_in[6];
  const float* b2  = (const float*)d_in[7];
  const float* w3  = (const float*)d_in[8];
  const float* b3  = (const float*)d_in[9];
  const float* si0 = (const float*)d_in[10];
  const float* si1 = (const float*)d_in[11];
  const float* si2 = (const float*)d_in[12];
  float* out = (float*)d_out;

  const int N = in_sizes[0] / 120;
  const int E = in_sizes[2] / 9;
  const int W3N = in_sizes[8];          // 64*3456

  float*  agg = (float*)d_ws;
  __bf16* w3b = (__bf16*)((char*)d_ws + (size_t)N * 120 * sizeof(float));
  hipMemsetAsync(agg, 0, (size_t)N * 120 * sizeof(float), stream);

  CgPack cg;
  build_cg(&cg);

  conv_w3<<<(W3N + 255) / 256, 256, 0, stream>>>(w3, w3b, W3N);
  tp_fused<<<E / 32, NT, 0, stream>>>(nf, ei, sh, rad, w1, b1, w2, b2, w3b, b3, agg, E, cg);
  si_kernel<<<N, 128, 0, stream>>>(agg, nf, si0, si1, si2, out);
}

// Round 7
// 407.577 us; speedup vs baseline: 1.0540x; 1.0540x over previous
//
#include <hip/hip_runtime.h>
#include <hip/hip_bf16.h>
#include <cmath>
#include <complex>

#define NT 512

typedef __bf16 bf16x8 __attribute__((ext_vector_type(8)));
typedef float  f32x4  __attribute__((ext_vector_type(4)));

struct CgPack { float v[363]; };

// ======================= host-side Wigner 3j (e3nn convention) =======================
static double factd(int n) { double r = 1.0; for (int i = 2; i <= n; ++i) r *= i; return r; }

static void su2_cg(int j1, int j2, int j3, double C[5][5][5]) {
  for (int a = 0; a < 5; ++a) for (int b = 0; b < 5; ++b) for (int c = 0; c < 5; ++c) C[a][b][c] = 0.0;
  for (int m1 = -j1; m1 <= j1; ++m1)
    for (int m2 = -j2; m2 <= j2; ++m2) {
      int m3 = m1 + m2;
      if (m3 < -j3 || m3 > j3) continue;
      int vmin = -j1 + j2 + m3; if (-j1 + m1 > vmin) vmin = -j1 + m1; if (vmin < 0) vmin = 0;
      int vmax = j2 + j3 + m1; if (j3 - j1 + j2 < vmax) vmax = j3 - j1 + j2; if (j3 + m3 < vmax) vmax = j3 + m3;
      double c = std::sqrt((2.0 * j3 + 1.0) *
            factd(j3 + j1 - j2) * factd(j3 - j1 + j2) * factd(j1 + j2 - j3) * factd(j3 + m3) * factd(j3 - m3) /
            (factd(j1 + j2 + j3 + 1) * factd(j1 - m1) * factd(j1 + m1) * factd(j2 - m2) * factd(j2 + m2)));
      double S = 0.0;
      for (int v = vmin; v <= vmax; ++v) {
        double t = factd(j2 + j3 + m1 - v) * factd(j1 - m1 + v) /
                   (factd(v) * factd(j3 - j1 + j2 - v) * factd(j3 + m3 - v) * factd(v + j1 - j2 - m3));
        S += (((v + j2 + m2) & 1) ? -t : t);
      }
      C[j1 + m1][j2 + m2][j3 + m3] = c * S;
    }
}

typedef std::complex<double> cd;
static void qmat(int l, cd q[5][5]) {
  for (int a = 0; a < 5; ++a) for (int b = 0; b < 5; ++b) q[a][b] = cd(0.0, 0.0);
  const double is2 = 1.0 / std::sqrt(2.0);
  for (int m = -l; m < 0; ++m) { q[l + m][l - m] = cd(is2, 0.0); q[l + m][l + m] = cd(0.0, -is2); }
  q[l][l] = cd(1.0, 0.0);
  for (int m = 1; m <= l; ++m) {
    double sg = (m & 1) ? -1.0 : 1.0;
    q[l + m][l + m] = cd(sg * is2, 0.0);
    q[l + m][l - m] = cd(0.0, sg * is2);
  }
  cd ph(1.0, 0.0); const cd mi(0.0, -1.0);
  for (int t = 0; t < l; ++t) ph *= mi;   // (-i)^l
  for (int a = 0; a <= 2 * l; ++a) for (int b = 0; b <= 2 * l; ++b) q[a][b] *= ph;
}

static void w3j_fill(int l1, int l2, int l3, float* outp) {
  double C[5][5][5]; su2_cg(l1, l2, l3, C);
  cd q1[5][5], q2[5][5], q3[5][5];
  qmat(l1, q1); qmat(l2, q2); qmat(l3, q3);
  const int d1 = 2 * l1 + 1, d2 = 2 * l2 + 1, d3 = 2 * l3 + 1;
  double R[5][5][5]; double nrm = 0.0;
  for (int j = 0; j < d1; ++j)
    for (int L = 0; L < d2; ++L)
      for (int m = 0; m < d3; ++m) {
        cd s(0.0, 0.0);
        for (int i = 0; i < d1; ++i)
          for (int k = 0; k < d2; ++k)
            for (int n = 0; n < d3; ++n)
              s += q1[i][j] * q2[k][L] * std::conj(q3[n][m]) * C[i][k][n];
        R[j][L][m] = s.real();
        nrm += s.real() * s.real();
      }
  const double inv = 1.0 / std::sqrt(nrm);
  for (int j = 0; j < d1; ++j)
    for (int L = 0; L < d2; ++L)
      for (int m = 0; m < d3; ++m)
        outp[(j * d2 + L) * d3 + m] = (float)(R[j][L][m] * inv);
}

static void build_cg(CgPack* cg) {
  const int L1[11] = {0,0,0,1,1,1,1,2,2,2,2};
  const int L2[11] = {0,1,2,0,1,1,2,0,1,2,2};
  const int L3[11] = {0,1,2,1,0,2,1,2,1,0,2};
  const int CGO[11]= {0,1,10,35,44,53,98,143,168,213,238};
  for (int p = 0; p < 11; ++p) w3j_fill(L1[p], L2[p], L3[p], &cg->v[CGO[p]]);
}

// ======================= device-side path constants =======================
constexpr int cP_l1[11] = {0,0,0,1,1,1,1,2,2,2,2};
constexpr int cP_l2[11] = {0,1,2,0,1,1,2,0,1,2,2};
constexpr int cP_l3[11] = {0,1,2,1,0,2,1,2,1,0,2};
constexpr int cP_wo[11] = {0,1024,1536,1792,2048,2560,2688,2944,3008,3136,3392};
constexpr int cP_cgo[11]= {0,1,10,35,44,53,98,143,168,213,238};
constexpr int mul_of_l(int l)    { return l == 0 ? 32 : (l == 1 ? 16 : 8); }
constexpr int off_in_of_l(int l) { return l == 0 ? 0  : (l == 1 ? 32 : 80); }
constexpr int off_sh_of_l(int l) { return l == 0 ? 0  : (l == 1 ? 1  : 4); }

__device__ __forceinline__ float silu_f(float x) { return x / (1.0f + __expf(-x)); }

// one 16-col x 16-edge MFMA tile + immediate register contract.
// bias b3 (LDS-staged) folded into the accumulator init.
template<int wo, int m3, int d3>
__device__ __forceinline__ void tile_mm(
    const __bf16* __restrict__ w3b, const float* b3s,
    const float* tmpw, const bf16x8 hB0, const bf16x8 hB1,
    const int u0, const int tt, const int uu, const int lr, const int lc,
    float (&acc)[4*d3])
{
  const int cb = wo + u0*m3 + tt*16;                    // global col base of tile
  const float4 b4 = *(const float4*)(b3s + cb + lr*4);  // bias (LDS broadcast)
  const __bf16* ap = w3b + (size_t)(cb + lc)*64 + lr*8; // A = w3 tile
  const bf16x8 a0 = *(const bf16x8*)ap;                 // k = lr*8..+8
  const bf16x8 a1 = *(const bf16x8*)(ap + 32);          // k = 32+lr*8..+8
  f32x4 dd = {b4.x, b4.y, b4.z, b4.w};
  dd = __builtin_amdgcn_mfma_f32_16x16x32_bf16(a0, hB0, dd, 0, 0, 0);
  dd = __builtin_amdgcn_mfma_f32_16x16x32_bf16(a1, hB1, dd, 0, 0, 0);
  // D[w3col = lr*4+r][edge = lc]; dd already includes b3
  float tv[d3];
  #pragma unroll
  for (int k = 0; k < d3; ++k) tv[k] = tmpw[(uu*d3 + k)*16 + lc];
  #pragma unroll
  for (int r = 0; r < 4; ++r) {
    #pragma unroll
    for (int k = 0; k < d3; ++k) acc[r*d3 + k] += dd[r] * tv[k];
  }
}

// one tensor-product path, fully wave-local; wave handles u-blocks ub0, ub0+ubstep, ...
template<int P>
__device__ __forceinline__ void wave_path(
    const CgPack& cg, const __bf16* __restrict__ w3b, const float* b3s,
    float (&x1s)[32][124], float (&x2s)[32][13],
    float* tmpw, float (&msg)[32][121],
    const bf16x8 hB0, const bf16x8 hB1, const int g, const int lane,
    const int ub0, const int ubstep)
{
  constexpr int l1 = cP_l1[P], l2 = cP_l2[P], l3 = cP_l3[P];
  constexpr int m1 = mul_of_l(l1), m3 = mul_of_l(l3);
  constexpr int d1 = 2*l1+1, d2 = 2*l2+1, d3 = 2*l3+1;
  constexpr int off1 = off_in_of_l(l1);
  constexpr int off2 = off_sh_of_l(l2);
  constexpr int off3 = off_in_of_l(l3);
  constexpr int wo = cP_wo[P], cgo = cP_cgo[P];
  constexpr float coeff = (l3==0) ? 0.13363062095621219f
                         : (l3==1) ? 0.20412414523193154f
                                   : 0.27950849718747373f;
  constexpr int UBLK = 4;                      // u's per tmp block (tmp rows = 4*d3 <= 20)
  constexpr int NUB  = m1 / UBLK;
  constexpr int NTIL = UBLK * m3 / 16;         // 16-col tiles per u-block: 8/4/2

  const int lr = lane >> 4, lc = lane & 15;
  const int e  = g*16 + lc;                    // this lane's edge (block-local)

  float accA[4*d3];
  float accB[(m3==32) ? 4 : 1];
  #pragma unroll
  for (int i = 0; i < 4*d3; ++i) accA[i] = 0.0f;
  #pragma unroll
  for (int i = 0; i < ((m3==32) ? 4 : 1); ++i) accB[i] = 0.0f;

  for (int ub = ub0; ub < NUB; ub += ubstep) {
    const int u0 = ub * UBLK;
    // ---- tmp build (wave-local LDS): 64 lanes = 16 edges x 4 u's, one pass
    {
      const int te = lane & 15, uu = lane >> 4;
      const float* xr = &x1s[g*16 + te][off1 + (u0 + uu)*d1];
      float t[d3];
      #pragma unroll
      for (int k = 0; k < d3; ++k) t[k] = 0.0f;
      #pragma unroll
      for (int i = 0; i < d1; ++i) {
        const float a = xr[i];
        #pragma unroll
        for (int j = 0; j < d2; ++j) {
          const float ab = a * x2s[g*16 + te][off2 + j];
          #pragma unroll
          for (int k = 0; k < d3; ++k) t[k] += ab * cg.v[cgo + (i*d2 + j)*d3 + k];
        }
      }
      #pragma unroll
      for (int k = 0; k < d3; ++k) tmpw[(uu*d3 + k)*16 + te] = t[k];
    }
    // (same-wave LDS producer/consumer: DS ops in order; compiler inserts lgkmcnt waits)

    // ---- tile loop: MFMA + immediate contract
    if constexpr (m3 == 32) {
      #pragma unroll
      for (int tt = 0; tt < NTIL; tt += 2) {
        tile_mm<wo, m3, d3>(w3b, b3s, tmpw, hB0, hB1, u0, tt,   tt>>1, lr, lc, accA);
        tile_mm<wo, m3, d3>(w3b, b3s, tmpw, hB0, hB1, u0, tt+1, tt>>1, lr, lc, accB);
      }
    } else {
      #pragma unroll
      for (int tt = 0; tt < NTIL; ++tt) {
        const int uu = (m3 == 16) ? tt : (2*tt + (lr >> 1));
        tile_mm<wo, m3, d3>(w3b, b3s, tmpw, hB0, hB1, u0, tt, uu, lr, lc, accA);
      }
    }
  }

  // ---- flush into msg (LDS atomics)
  if constexpr (m3 == 16) {
    #pragma unroll
    for (int r = 0; r < 4; ++r)
      #pragma unroll
      for (int k = 0; k < d3; ++k)
        atomicAdd(&msg[e][off3 + (lr*4 + r)*d3 + k], coeff * accA[r*d3 + k]);
  } else if constexpr (m3 == 8) {
    #pragma unroll
    for (int i = 0; i < 4*d3; ++i) accA[i] += __shfl_xor(accA[i], 32, 64);
    if (lane < 32) {   // lr in {0,1}: v = lr*4+r covers 0..7
      #pragma unroll
      for (int r = 0; r < 4; ++r)
        #pragma unroll
        for (int k = 0; k < d3; ++k)
          atomicAdd(&msg[e][off3 + (lr*4 + r)*d3 + k], coeff * accA[r*d3 + k]);
    }
  } else {  // m3 == 32, d3 == 1
    #pragma unroll
    for (int r = 0; r < 4; ++r) {
      atomicAdd(&msg[e][off3 +      lr*4 + r], coeff * accA[r]);
      atomicAdd(&msg[e][off3 + 16 + lr*4 + r], coeff * accB[r]);
    }
  }
}

// ======================= w3 -> bf16 (col-major, K-contiguous) =======================
__global__ __launch_bounds__(256)
void conv_w3(const float* __restrict__ w3, __bf16* __restrict__ w3b, const int n) {
  const int idx = blockIdx.x * 256 + threadIdx.x;
  if (idx >= n) return;
  const int k = idx / 3456, col = idx - k * 3456;
  w3b[(size_t)col * 64 + k] = (__bf16)w3[idx];
}

// ======================= fused MLP + TP + scatter kernel =======================
// 32 edges/block, 8 waves: wave = (edge-group g in {0,1}) x (col-quarter q in {0..3})
__global__ __launch_bounds__(NT, 4)
void tp_fused(const float* __restrict__ nf, const int* __restrict__ eidx,
              const float* __restrict__ sh, const float* __restrict__ rad,
              const float* __restrict__ w1, const float* __restrict__ b1,
              const float* __restrict__ w2, const float* __restrict__ b2,
              const __bf16* __restrict__ w3b, const float* __restrict__ b3,
              float* __restrict__ agg, const int E, const CgPack cg)
{
  __shared__ float msg[32][121];      // per-edge message accumulator (15.5 KB); prologue: h1T
  __shared__ float x1s[32][124];      // gathered node features (15.9 KB)
  __shared__ float x2s[32][13];       // edge SH (1.7 KB)
  __shared__ float b3s[3456];         // staged bias (13.8 KB)
  __shared__ float tmparea[8][320];   // per-wave tmp regions (10.24 KB); prologue: h2b
  __shared__ int   esrc[32], edst[32];

  const int tid  = threadIdx.x;
  const int lane = tid & 63, w = tid >> 6;
  const int g = w & 1, q = w >> 1;
  const int lr = lane >> 4, lc = lane & 15;
  const int e0 = blockIdx.x * 32;

  float*  h1T = &msg[0][0];                    // 64x32 f32 (8 KB), h1T[c*32+e]
  __bf16* h2b = (__bf16*)&tmparea[0][0];       // 32x64 bf16 (4 KB), h2b[e*64+k]

  // ---- phase A0: edge indices
  if (tid < 32)      esrc[tid]      = eidx[e0 + tid];
  else if (tid < 64) edst[tid - 32] = eidx[E + e0 + tid - 32];
  __syncthreads();

  // ---- phase A: h1 = silu(rad@w1+b1) -> h1T, x1 gather, x2 + b3 stage
  for (int idx = tid; idx < 64 * 32; idx += NT) {
    const int c = idx >> 5, e = idx & 31;
    const float4* r4 = (const float4*)(rad + (size_t)(e0 + e) * 8);
    const float4 ra = r4[0], rb = r4[1];
    float a = b1[c];
    a += ra.x * w1[0*64+c] + ra.y * w1[1*64+c] + ra.z * w1[2*64+c] + ra.w * w1[3*64+c];
    a += rb.x * w1[4*64+c] + rb.y * w1[5*64+c] + rb.z * w1[6*64+c] + rb.w * w1[7*64+c];
    h1T[c * 32 + e] = silu_f(a);
  }
  for (int idx = tid; idx < 32 * 30; idx += NT) {
    const int e = idx / 30, qq = idx - e * 30;
    *(float4*)(&x1s[e][qq * 4]) = *(const float4*)(nf + (size_t)esrc[e] * 120 + qq * 4);
  }
  for (int idx = tid; idx < 864; idx += NT)
    *(float4*)(&b3s[idx * 4]) = *(const float4*)(b3 + idx * 4);
  for (int idx = tid; idx < 32 * 9; idx += NT) {
    const int e = idx / 9, j = idx - e * 9;
    x2s[e][j] = sh[(size_t)(e0 + e) * 9 + j];
  }
  __syncthreads();

  // ---- phase B: h2 = silu(h1@w2+b2) -> h2b[e][k] (bf16, k-contiguous); 512 tasks = 1 pass
  {
    const int c = tid >> 3, eq = (tid & 7) * 4;
    float a0 = b2[c], a1 = b2[c], a2 = b2[c], a3 = b2[c];
    #pragma unroll 8
    for (int i = 0; i < 64; ++i) {
      const float wv = w2[i * 64 + c];
      const float4 h4 = *(const float4*)(&h1T[i * 32 + eq]);
      a0 += h4.x * wv; a1 += h4.y * wv; a2 += h4.z * wv; a3 += h4.w * wv;
    }
    h2b[(eq+0)*64 + c] = (__bf16)silu_f(a0);
    h2b[(eq+1)*64 + c] = (__bf16)silu_f(a1);
    h2b[(eq+2)*64 + c] = (__bf16)silu_f(a2);
    h2b[(eq+3)*64 + c] = (__bf16)silu_f(a3);
  }
  __syncthreads();

  // ---- per-wave B-fragments: lane holds h2[e = g*16+lc][k = kb*32 + lr*8 + j]
  const bf16x8 hB0 = *(const bf16x8*)(h2b + (g*16 + lc)*64 +      lr*8);
  const bf16x8 hB1 = *(const bf16x8*)(h2b + (g*16 + lc)*64 + 32 + lr*8);
  // zero msg (h1T dead now)
  for (int idx = tid; idx < 32 * 121; idx += NT) (&msg[0][0])[idx] = 0.0f;
  __syncthreads();   // h2b consumed + msg zeroed; tmparea free

  float* tmpw = tmparea[w];

  // ---- paths: u-blocks round-robin across the 4 quarters (zero duplication)
  wave_path<0>(cg, w3b, b3s, x1s, x2s, tmpw, msg, hB0, hB1, g, lane, q, 4);
  wave_path<1>(cg, w3b, b3s, x1s, x2s, tmpw, msg, hB0, hB1, g, lane, q, 4);
  wave_path<2>(cg, w3b, b3s, x1s, x2s, tmpw, msg, hB0, hB1, g, lane, q, 4);
  wave_path<3>(cg, w3b, b3s, x1s, x2s, tmpw, msg, hB0, hB1, g, lane, q, 4);
  wave_path<4>(cg, w3b, b3s, x1s, x2s, tmpw, msg, hB0, hB1, g, lane, q, 4);
  wave_path<5>(cg, w3b, b3s, x1s, x2s, tmpw, msg, hB0, hB1, g, lane, q, 4);
  wave_path<6>(cg, w3b, b3s, x1s, x2s, tmpw, msg, hB0, hB1, g, lane, q, 4);
  if (q < 2) {
    wave_path<7>(cg, w3b, b3s, x1s, x2s, tmpw, msg, hB0, hB1, g, lane, q, 2);
    wave_path<9>(cg, w3b, b3s, x1s, x2s, tmpw, msg, hB0, hB1, g, lane, q, 2);
  } else {
    wave_path<8>(cg, w3b, b3s, x1s, x2s, tmpw, msg, hB0, hB1, g, lane, q-2, 2);
    wave_path<10>(cg, w3b, b3s, x1s, x2s, tmpw, msg, hB0, hB1, g, lane, q-2, 2);
  }
  __syncthreads();   // all msg flushes complete

  // ---- scatter: agg[dst] += msg
  for (int idx = tid; idx < 32 * 120; idx += NT) {
    const int e = idx / 120, d = idx - e * 120;
    atomicAdd(&agg[(size_t)edst[e] * 120 + d], msg[e][d]);
  }
}

// ======================= self-interaction + residual =======================
__global__ __launch_bounds__(128)
void si_kernel(const float* __restrict__ agg, const float* __restrict__ nf,
               const float* __restrict__ w0, const float* __restrict__ wl1,
               const float* __restrict__ wl2, float* __restrict__ out)
{
  __shared__ float a[120];
  const int n = blockIdx.x, tid = threadIdx.x;
  if (tid < 120) a[tid] = agg[(size_t)n * 120 + tid];
  __syncthreads();
  if (tid >= 120) return;
  float s = 0.0f;
  if (tid < 32) {
    const int v = tid;
    #pragma unroll
    for (int u = 0; u < 32; ++u) s += a[u] * w0[u * 32 + v];
    s *= 0.17677669529663687f;    // 1/sqrt(32)
  } else if (tid < 80) {
    const int r = tid - 32, v = r / 3, k = r - 3 * v;
    #pragma unroll
    for (int u = 0; u < 16; ++u) s += a[32 + u * 3 + k] * wl1[u * 16 + v];
    s *= 0.25f;                   // 1/sqrt(16)
  } else {
    const int r = tid - 80, v = r / 5, k = r - 5 * v;
    #pragma unroll
    for (int u = 0; u < 8; ++u) s += a[80 + u * 5 + k] * wl2[u * 8 + v];
    s *= 0.35355339059327373f;    // 1/sqrt(8)
  }
  out[(size_t)n * 120 + tid] = s + nf[(size_t)n * 120 + tid];
}

// ======================= launch =======================
extern "C" void kernel_launch(void* const* d_in, const int* in_sizes, int n_in,
                              void* d_out, int out_size, void* d_ws, size_t ws_size,
                              hipStream_t stream) {
  const float* nf  = (const float*)d_in[0];
  const int*   ei  = (const int*)  d_in[1];
  const float* sh  = (const float*)d_in[2];
  const float* rad = (const float*)d_in[3];
  const float* w1  = (const float*)d_in[4];
  const float* b1  = (const float*)d_in[5];
  const float* w2  = (const float*)d_in[6];
  const float* b2  = (const float*)d_in[7];
  const float* w3  = (const float*)d_in[8];
  const float* b3  = (const float*)d_in[9];
  const float* si0 = (const float*)d_in[10];
  const float* si1 = (const float*)d_in[11];
  const float* si2 = (const float*)d_in[12];
  float* out = (float*)d_out;

  const int N = in_sizes[0] / 120;
  const int E = in_sizes[2] / 9;
  const int W3N = in_sizes[8];          // 64*3456

  float*  agg = (float*)d_ws;
  __bf16* w3b = (__bf16*)((char*)d_ws + (size_t)N * 120 * sizeof(float));
  hipMemsetAsync(agg, 0, (size_t)N * 120 * sizeof(float), stream);

  CgPack cg;
  build_cg(&cg);

  conv_w3<<<(W3N + 255) / 256, 256, 0, stream>>>(w3, w3b, W3N);
  tp_fused<<<E / 32, NT, 0, stream>>>(nf, ei, sh, rad, w1, b1, w2, b2, w3b, b3, agg, E, cg);
  si_kernel<<<N, 128, 0, stream>>>(agg, nf, si0, si1, si2, out);
}